// Round 1
// baseline (1923.124 us; speedup 1.0000x reference)
//
#include <hip/hip_runtime.h>

#define D_IN 2312
#define HID  800
#define NCLS 10
#define BATCH 128
#define TSTEPS 300
#define WIN  50

// ---------------------------------------------------------------------------
// Kernel 1: produce output X = zeros with input pasted at [idx, idx+50)
// outX layout: [B][D_IN][T] fp32, thread handles 4 consecutive t (float4 store)
// ---------------------------------------------------------------------------
__global__ __launch_bounds__(256) void paste_kernel(
    const float* __restrict__ inp,   // [B][D_IN][WIN]
    const int*   __restrict__ idx,   // [B]
    float*       __restrict__ outX)  // [B][D_IN][T]
{
  int gid  = blockIdx.x * 256 + threadIdx.x;   // over B*D_IN*(T/4)
  int q    = gid % (TSTEPS / 4);
  int rest = gid / (TSTEPS / 4);
  int d    = rest % D_IN;
  int b    = rest / D_IN;
  int ib   = idx[b];
  const float* ip = inp + (size_t)b * (D_IN * WIN) + (size_t)d * WIN;
  int t0 = q * 4;
  float v[4];
#pragma unroll
  for (int e = 0; e < 4; ++e) {
    unsigned w = (unsigned)(t0 + e - ib);
    v[e] = (w < (unsigned)WIN) ? ip[w] : 0.f;
  }
  float4* dst = (float4*)(outX + (size_t)b * (D_IN * TSTEPS) + (size_t)d * TSTEPS + t0);
  *dst = make_float4(v[0], v[1], v[2], v[3]);
}

// ---------------------------------------------------------------------------
// Kernel 2: P[(b*50+s)][j] = sum_d input[b][d][s] * W1[j][d]
// M=6400 (rows b,s), N=800 (j), K=2312 (d). fp32, 64x64 tile, BK=32,
// 256 threads, 4x4 microtile per thread.
// ---------------------------------------------------------------------------
__global__ __launch_bounds__(256) void gemm_kernel(
    const float* __restrict__ inp,   // [B][D_IN][WIN] -> A[(b,s)][d] = inp[b*115600 + d*50 + s]
    const float* __restrict__ W1,    // [HID][D_IN]
    float*       __restrict__ P)     // [6400][HID]
{
  __shared__ float As[32][64];
  __shared__ float Bs[32][66];   // padded: write stride 66 -> 2 lanes/bank (free)

  int t  = threadIdx.x;
  int r0 = blockIdx.x * 64;      // row tile (100 tiles, M=6400 exact)
  int n0 = blockIdx.y * 64;      // col tile (13 tiles, last partial)

  // A-load: thread-invariant row base
  int mm = t & 63;
  int r  = r0 + mm;
  int bb = r / 50;
  int ss = r - bb * 50;
  const float* aptr = inp + (size_t)bb * (D_IN * WIN) + ss;   // index by k*50

  int bk      = t & 31;   // k within chunk for B loads
  int bn_base = t >> 5;   // 0..7

  int tm = (t & 15) * 4;  // micro-tile m base
  int tn = (t >> 4) * 4;  // micro-tile n base

  float acc[4][4] = {};

  for (int k0 = 0; k0 < D_IN; k0 += 32) {
#pragma unroll
    for (int rr = 0; rr < 8; ++rr) {
      int kk = rr * 4 + (t >> 6);
      int k  = k0 + kk;
      As[kk][mm] = (k < D_IN) ? aptr[k * WIN] : 0.f;
    }
#pragma unroll
    for (int rr = 0; rr < 8; ++rr) {
      int nn = rr * 8 + bn_base;
      int n  = n0 + nn;
      int k  = k0 + bk;
      Bs[bk][nn] = (n < HID && k < D_IN) ? W1[(size_t)n * D_IN + k] : 0.f;
    }
    __syncthreads();
#pragma unroll
    for (int kk = 0; kk < 32; ++kk) {
      float4 av = *(const float4*)&As[kk][tm];
      float b0v = Bs[kk][tn + 0];
      float b1v = Bs[kk][tn + 1];
      float b2v = Bs[kk][tn + 2];
      float b3v = Bs[kk][tn + 3];
      acc[0][0] += av.x * b0v; acc[0][1] += av.x * b1v; acc[0][2] += av.x * b2v; acc[0][3] += av.x * b3v;
      acc[1][0] += av.y * b0v; acc[1][1] += av.y * b1v; acc[1][2] += av.y * b2v; acc[1][3] += av.y * b3v;
      acc[2][0] += av.z * b0v; acc[2][1] += av.z * b1v; acc[2][2] += av.z * b2v; acc[2][3] += av.z * b3v;
      acc[3][0] += av.w * b0v; acc[3][1] += av.w * b1v; acc[3][2] += av.w * b2v; acc[3][3] += av.w * b3v;
    }
    __syncthreads();
  }

  if (n0 + tn < HID) {
#pragma unroll
    for (int i = 0; i < 4; ++i) {
      int row = r0 + tm + i;
      float4* dst = (float4*)&P[(size_t)row * HID + n0 + tn];
      *dst = make_float4(acc[i][0], acc[i][1], acc[i][2], acc[i][3]);
    }
  }
}

// ---------------------------------------------------------------------------
// Kernel 3: the sequential recurrence. One block (256 thr) per batch element.
// h1 state (800) distributed: thread t owns j = t, t+256, t+512 (+768 if t<32).
// W2 (10 rows) + Wc[0:800] staged in LDS as sWT[j][k], k=0..10.
// Threads 0..9 own h2m/h2s/sum2[k]; thread 10 owns cm/cs/bgt.
// ---------------------------------------------------------------------------
__global__ __launch_bounds__(256) void recur_kernel(
    const float* __restrict__ P,    // [6400][HID]
    const float* __restrict__ W2,   // [NCLS][HID]
    const float* __restrict__ b2,   // [NCLS]
    const float* __restrict__ Wc,   // [HID+4]
    const float* __restrict__ bc,   // [1]
    const float* __restrict__ b1,   // [HID]
    const int*   __restrict__ idx,  // [B]
    float*       __restrict__ out)  // [B][NCLS] (rate)
{
  __shared__ float sWT[HID][11];
  __shared__ float sRed[4][11];
  __shared__ float sCs;
  __shared__ float sBgt;

  int t = threadIdx.x;
  int b = blockIdx.x;

  for (int i = t; i < HID * 11; i += 256) {
    int j = i / 11;
    int k = i - j * 11;
    sWT[j][k] = (k < 10) ? W2[k * HID + j] : Wc[j];
  }
  if (t == 0) sCs = 0.f;

  int myidx = idx[b];

  float m[4] = {0.f, 0.f, 0.f, 0.f};
  float s[4] = {0.f, 0.f, 0.f, 0.f};
  float b1r[4] = {0.f, 0.f, 0.f, 0.f};
#pragma unroll
  for (int r = 0; r < 4; ++r) {
    int j = t + 256 * r;
    if (j < HID) b1r[r] = b1[j];
  }

  float h2m = 0.f, h2s = 0.f, sum2 = 0.f, b2r = 0.f;
  float cm = 0.f, csr = 0.f, bgt = 1.f, bcv = 0.f;
  float wcf0 = 0.f, wcf1 = 0.f, wcf2 = 0.f, wcf3 = 0.f;
  if (t < 10) b2r = b2[t];
  if (t == 10) {
    bcv  = bc[0];
    wcf0 = Wc[HID + 0];
    wcf1 = Wc[HID + 1];
    wcf2 = Wc[HID + 2];
    wcf3 = Wc[HID + 3];
  }

  const float* Pb = P + (size_t)b * WIN * HID;
  int lane = t & 63, wid = t >> 6;

  __syncthreads();

  for (int step = 0; step < TSTEPS; ++step) {
    float gate = (step == 0) ? 1.f : sCs;       // cs_prev, broadcast via LDS
    unsigned w = (unsigned)(step - myidx);
    bool haveP = (w < (unsigned)WIN) && (gate != 0.f);
    const float* Prow = Pb + (size_t)w * HID;

    float acc[11];
#pragma unroll
    for (int k = 0; k < 11; ++k) acc[k] = 0.f;

    auto h1body = [&](int r, int j) {
      float pv = haveP ? Prow[j] : 0.f;
      float mv = m[r] * 0.1f * (1.f - s[r]) + pv + b1r[r];
      m[r] = mv;
      float sp = (mv > 0.5f) ? 1.f : 0.f;
      s[r] = sp;
      if (sp != 0.f) {
#pragma unroll
        for (int k = 0; k < 11; ++k) acc[k] += sWT[j][k];
      }
    };
    h1body(0, t);
    h1body(1, t + 256);
    h1body(2, t + 512);
    if (t < 32) h1body(3, t + 768);

    // wave-level reduce (64 lanes), then 4 partials per output in LDS
#pragma unroll
    for (int k = 0; k < 11; ++k) {
      float v = acc[k];
      v += __shfl_down(v, 32);
      v += __shfl_down(v, 16);
      v += __shfl_down(v, 8);
      v += __shfl_down(v, 4);
      v += __shfl_down(v, 2);
      v += __shfl_down(v, 1);
      if (lane == 0) sRed[wid][k] = v;
    }
    __syncthreads();

    if (t < 11) {
      float dot = sRed[0][t] + sRed[1][t] + sRed[2][t] + sRed[3][t];
      if (t < 10) {
        h2m = h2m * 0.1f * (1.f - h2s) + dot + b2r;
        h2s = (h2m > 0.5f) ? 1.f : 0.f;
        sum2 += h2s;
      } else {
        // thread 10: budget (uses cs BEFORE update), then ctrl neuron
        bgt += (csr == 1.f) ? 1.f : 0.f;
        float fq = wcf0;
        if ((step % 2) == 0)   fq += wcf1;
        if ((step % 10) == 0)  fq += wcf2;
        if ((step % 100) == 0) fq += wcf3;
        cm = cm * 0.1f * (1.f - csr) + dot + fq + bcv;
        csr = (cm > 0.5f) ? 1.f : 0.f;
        sCs = csr;
      }
    }
    __syncthreads();
  }

  if (t == 10) sBgt = bgt;
  __syncthreads();
  if (t < 10) out[b * NCLS + t] = sum2 / sBgt;
}

// ---------------------------------------------------------------------------
extern "C" void kernel_launch(void* const* d_in, const int* in_sizes, int n_in,
                              void* d_out, int out_size, void* d_ws, size_t ws_size,
                              hipStream_t stream) {
  const float* inp = (const float*)d_in[0];
  // d_in[1] = X (zeros) — regenerated directly into the output, unused here
  const int*   idx = (const int*)d_in[2];
  const float* W1  = (const float*)d_in[3];
  const float* b1  = (const float*)d_in[4];
  const float* W2  = (const float*)d_in[5];
  const float* b2  = (const float*)d_in[6];
  const float* Wc  = (const float*)d_in[7];
  const float* bc  = (const float*)d_in[8];

  float* out = (float*)d_out;              // [0,1280): rate ; [1280, ...): X
  float* P   = (float*)d_ws;               // [6400][800] fp32 = 20.48 MB

  // GEMM first (longest pole), then paste, then the recurrence (depends on P)
  gemm_kernel<<<dim3(100, 13), 256, 0, stream>>>(inp, W1, P);

  int paste_blocks = (BATCH * D_IN * (TSTEPS / 4)) / 256;   // 86700
  paste_kernel<<<paste_blocks, 256, 0, stream>>>(inp, idx, out + BATCH * NCLS);

  recur_kernel<<<BATCH, 256, 0, stream>>>(P, W2, b2, Wc, bc, b1, idx, out);
}